// Round 3
// baseline (75.663 us; speedup 1.0000x reference)
//
#include <hip/hip_runtime.h>

// B=32, L=4096, V=10, F=1024, D=64
// out[1, b*D+d, l] = dot(fp_table[idx[b,l],:], W[d,:]) + bias[d]
// V=10 => each output row (b,d) needs only P[d,v] = dot(fp_table[v],W[d])+b[d],
// a 10-entry table. One block per row: compute the 10 dots (10K MACs, cheap),
// then gather the 4096-elem row with int4 idx loads + NT float4 stores.
#define B_SIZE 32
#define L_SIZE 4096
#define V_SIZE 10
#define F_SIZE 1024
#define D_SIZE 64

// clang-native vector type for __builtin_nontemporal_store
typedef float nt_float4 __attribute__((ext_vector_type(4)));

__global__ __launch_bounds__(256) void fused_fp_embed_kernel(
    const int* __restrict__ idx,
    const float* __restrict__ fp_table,
    const float* __restrict__ W,
    const float* __restrict__ bias,
    float* __restrict__ out) {
  const int r   = blockIdx.x;      // output row, 0..2047
  const int d   = r & 63;          // dim
  const int b   = r >> 6;          // batch
  const int tid = threadIdx.x;     // 0..255
  const int lane = tid & 63;
  const int wave = tid >> 6;

  // ---- Stage 1: P[d, v] for v=0..9 ----
  // Each thread handles one float4 of the F=1024 axis (256 threads * 4 = 1024).
  const float4 w4 = ((const float4*)(W + d * F_SIZE))[tid];
  float s[V_SIZE];
  #pragma unroll
  for (int v = 0; v < V_SIZE; ++v) {
    const float4 a = ((const float4*)(fp_table + v * F_SIZE))[tid];
    s[v] = a.x * w4.x + a.y * w4.y + a.z * w4.z + a.w * w4.w;
  }
  // Wave-level shuffle reduction (64 lanes) for each of the 10 partials.
  #pragma unroll
  for (int v = 0; v < V_SIZE; ++v) {
    #pragma unroll
    for (int off = 32; off > 0; off >>= 1)
      s[v] += __shfl_down(s[v], off, 64);
  }
  // Cross-wave: 4 waves x 10 values through LDS.
  __shared__ float red[4][V_SIZE];
  __shared__ float Pl[16];  // padded; only 0..9 used
  if (lane == 0) {
    #pragma unroll
    for (int v = 0; v < V_SIZE; ++v) red[wave][v] = s[v];
  }
  __syncthreads();
  if (tid < V_SIZE) {
    Pl[tid] = red[0][tid] + red[1][tid] + red[2][tid] + red[3][tid] + bias[d];
  }
  __syncthreads();

  // ---- Stage 2: gather the row ----
  // Row has L/4 = 1024 float4s; 256 threads -> 4 iterations, coalesced.
  const int4* idxr = (const int4*)(idx + b * L_SIZE);
  nt_float4* outr = (nt_float4*)(out + (size_t)r * L_SIZE);
  #pragma unroll
  for (int j = 0; j < 4; ++j) {
    const int c4 = tid + 256 * j;
    const int4 vi = idxr[c4];  // 16B coalesced, L2-hot (reused by 64 d's)
    nt_float4 o;
    o.x = Pl[vi.x];
    o.y = Pl[vi.y];
    o.z = Pl[vi.z];
    o.w = Pl[vi.w];
    // NT store: output (33.5 MB) > aggregate L2; skip write-allocate.
    __builtin_nontemporal_store(o, outr + c4);
  }
}

extern "C" void kernel_launch(void* const* d_in, const int* in_sizes, int n_in,
                              void* d_out, int out_size, void* d_ws, size_t ws_size,
                              hipStream_t stream) {
  const int*   idx      = (const int*)d_in[0];    // [B, L] int32
  const float* fp_table = (const float*)d_in[1];  // [V, F]
  const float* W        = (const float*)d_in[2];  // [D, F]
  const float* bias     = (const float*)d_in[3];  // [D]
  float* out = (float*)d_out;                     // [1, B*D, L] fp32

  fused_fp_embed_kernel<<<B_SIZE * D_SIZE, 256, 0, stream>>>(
      idx, fp_table, W, bias, out);
}